// Round 5
// baseline (3340.149 us; speedup 1.0000x reference)
//
#include <hip/hip_runtime.h>

#define NF 64
#define KEXP 50
#define TBL 2048
#define CUTF 5.0f
#define LOG2C 0.6931471805599453f
#define PPARTS 16           // dst-node partitions (agg slice ~1.6MB -> L2-resident)
#define NSUBW 8             // writer sub-buckets (blockIdx&7 ~ XCD)
#define SLOTS (PPARTS * NSUBW)
#define OFLOW_MAX (1 << 16)
#define MIN_CAP 14000       // mean 12.5k + ~13 sigma

__device__ __forceinline__ float sspf(float x) {
    return fmaxf(x, 0.0f) + log1pf(expf(-fabsf(x))) - LOG2C;
}

__device__ __forceinline__ float bcast(float v, int k) {
    return __int_as_float(__builtin_amdgcn_readlane(__float_as_int(v), k));
}

// ---------------------------------------------------------------------------
// interleaved lerp table: tab2[t][lane] = (filt_t[lane], filt_{t+1}[lane])
// ---------------------------------------------------------------------------
__global__ void build_tab2_k(const float* __restrict__ f_w1, const float* __restrict__ f_b1,
                             const float* __restrict__ f_w2, const float* __restrict__ f_b2,
                             float2* __restrict__ tab2) {
    __shared__ float rbf_s[KEXP];
    __shared__ float s_s[NF];
    const int t = blockIdx.x;
    const int f = threadIdx.x; // 0..63
    const float d = (float)t * (CUTF / (float)(TBL - 1));
    const float delta = CUTF / (float)(KEXP - 1);
    const float coeff = -0.5f / (delta * delta);
    if (f < KEXP) {
        float dd = d - (float)f * delta;
        rbf_s[f] = expf(coeff * dd * dd);
    }
    __syncthreads();
    float t1 = f_b1[f];
    for (int k = 0; k < KEXP; ++k) t1 = fmaf(rbf_s[k], f_w1[f * KEXP + k], t1);
    s_s[f] = sspf(t1);
    __syncthreads();
    float t2 = f_b2[f];
    for (int k = 0; k < NF; ++k) t2 = fmaf(s_s[k], f_w2[f * NF + k], t2);
    if (t < TBL - 1) tab2[(size_t)t * NF + f].x = t2;
    if (t > 0)       tab2[(size_t)(t - 1) * NF + f].y = t2;
}

// ---------------------------------------------------------------------------
// prep: h = x @ lin_w.T + lin_b  (wave/node, weights in VGPR, readlane bcast)
// ---------------------------------------------------------------------------
__global__ void __launch_bounds__(256) prep_k(
    const float* __restrict__ x, const float* __restrict__ w, const float* __restrict__ b,
    float* __restrict__ h, int n_nodes)
{
    const int tid = threadIdx.x;
    const int lane = tid & 63;
    float wreg[NF];
    #pragma unroll
    for (int k = 0; k < NF; k += 4) {
        float4 q = *(const float4*)(w + (size_t)lane * NF + k);
        wreg[k] = q.x; wreg[k + 1] = q.y; wreg[k + 2] = q.z; wreg[k + 3] = q.w;
    }
    const float bias = b[lane];
    const int nwaves = (gridDim.x * blockDim.x) >> 6;
    const int gw = (blockIdx.x * blockDim.x + tid) >> 6;
    for (int n = gw; n < n_nodes; n += nwaves) {
        const float xv = x[(size_t)n * NF + lane];
        float a0 = bias, a1 = 0.f, a2 = 0.f, a3 = 0.f;
        #pragma unroll
        for (int k = 0; k < NF; k += 4) {
            a0 = fmaf(bcast(xv, k),     wreg[k],     a0);
            a1 = fmaf(bcast(xv, k + 1), wreg[k + 1], a1);
            a2 = fmaf(bcast(xv, k + 2), wreg[k + 2], a2);
            a3 = fmaf(bcast(xv, k + 3), wreg[k + 3], a3);
        }
        h[(size_t)n * NF + lane] = (a0 + a1) + (a2 + a3);
    }
}

// ---------------------------------------------------------------------------
// scatter: bin 8B self-contained records into (dst-partition, writer) buckets
// rec = (src | i0<<20, dst | f15<<17)
// ---------------------------------------------------------------------------
__global__ void __launch_bounds__(256) scatter_k(const int* __restrict__ nbr,
                                                 const float* __restrict__ dist,
                                                 unsigned part_mul,
                                                 unsigned* __restrict__ gcur,
                                                 uint2* __restrict__ payload, int cap,
                                                 unsigned* __restrict__ oflow_cnt,
                                                 unsigned* __restrict__ oflow, int n_edges) {
    const unsigned sub = blockIdx.x & (NSUBW - 1);
    const float scale = (float)(TBL - 1) / CUTF;
    const int gt = blockIdx.x * blockDim.x + threadIdx.x;
    const int gs = gridDim.x * blockDim.x;
    for (int e = gt; e < n_edges; e += gs) {
        const unsigned dst = (unsigned)nbr[n_edges + e];
        const unsigned src = (unsigned)nbr[e];
        const float xx = dist[e] * scale;
        int i0 = (int)xx;
        i0 = max(0, min(i0, TBL - 2));
        const float fr = xx - (float)i0;
        const unsigned f15 = min((unsigned)(fr * 32768.0f), 32767u);
        const unsigned part = __umulhi(dst, part_mul);           // 0..PPARTS-1
        const unsigned slot = part * NSUBW + sub;
        const unsigned pos = atomicAdd(&gcur[slot], 1u);
        if ((int)pos < cap) {
            payload[(size_t)slot * cap + pos] =
                make_uint2(src | ((unsigned)i0 << 20), dst | (f15 << 17));
        } else {
            const unsigned oi = atomicAdd(oflow_cnt, 1u);
            if (oi < OFLOW_MAX) oflow[oi] = (unsigned)e;
        }
    }
}

// ---------------------------------------------------------------------------
// apply: streaming edge kernel with XCD-local global atomics.
// part = (blockIdx&7) + 8*(blockIdx>>11) so all atomics on one agg slice
// come from one XCD -> lines stay in its L2.
// ---------------------------------------------------------------------------
__global__ void __launch_bounds__(256) apply_k(const unsigned* __restrict__ gcur,
                                               const uint2* __restrict__ payload, int cap,
                                               const float* __restrict__ h,
                                               const float2* __restrict__ tab2,
                                               float* __restrict__ agg) {
    __shared__ uint2 rb[4][64];
    const int tid = threadIdx.x;
    const int lane = tid & 63;
    const int wid = tid >> 6;
    const int b = blockIdx.x;
    const int part = (b & 7) + 8 * (b >> 11);        // 0..15
    const int blkin = (b >> 3) & 255;                // 0..255 within partition
    const int gwave = blkin * 4 + wid;               // 0..1023
    const int nwave = 1024;

    for (int sb = 0; sb < NSUBW; ++sb) {
        const int slot = part * NSUBW + sb;
        const unsigned cnt = min(gcur[slot], (unsigned)cap);
        const uint2* pp = payload + (size_t)slot * cap;
        const unsigned nb = (cnt + 63u) >> 6;
        for (unsigned bidx = gwave; bidx < nb; bidx += nwave) {
            const unsigned base = bidx << 6;
            const int m = (int)min(64u, cnt - base);
            uint2 pl = make_uint2(0u, 0u);
            if (lane < m) pl = pp[base + lane];
            rb[wid][lane] = pl;          // per-wave region; intra-wave ordering only
            auto edge = [&](int j) {
                const uint2 r = rb[wid][j];              // uniform addr -> broadcast
                const unsigned src = r.x & 0x1FFFFu;
                const int      i0  = (int)(r.x >> 20);
                const unsigned dst = r.y & 0x1FFFFu;
                const float    fr  = (float)(r.y >> 17) * (1.0f / 32768.0f);
                const float2 t = tab2[(size_t)i0 * NF + lane];
                const float hv = h[(size_t)src * NF + lane];
                const float filt = fmaf(fr, t.y - t.x, t.x);
                atomicAdd(agg + (size_t)dst * NF + lane, hv * filt);
            };
            if (m == 64) {
                #pragma unroll 4
                for (int j = 0; j < 64; ++j) edge(j);
            } else {
                for (int j = 0; j < m; ++j) edge(j);
            }
        }
    }
}

// ---------------------------------------------------------------------------
// overflow fixup: global atomic adds (normally 0 edges)
// ---------------------------------------------------------------------------
__global__ void __launch_bounds__(256) oflow_fix_k(const unsigned* __restrict__ oflow_cnt,
                                                   const unsigned* __restrict__ oflow,
                                                   const int* __restrict__ nbr,
                                                   const float* __restrict__ dist,
                                                   const float* __restrict__ h,
                                                   const float2* __restrict__ tab2,
                                                   float* __restrict__ agg, int n_edges) {
    const unsigned cnt = min(*oflow_cnt, (unsigned)OFLOW_MAX);
    const int lane = threadIdx.x & 63;
    const int gw = (blockIdx.x * blockDim.x + threadIdx.x) >> 6;
    const int nw = (gridDim.x * blockDim.x) >> 6;
    const float scale = (float)(TBL - 1) / CUTF;
    for (unsigned t = gw; t < cnt; t += nw) {
        const unsigned e = oflow[t];
        const int sj = nbr[e];
        const int dj = nbr[n_edges + e];
        const float xx = dist[e] * scale;
        int i0 = (int)xx;
        i0 = max(0, min(i0, TBL - 2));
        const float fr = xx - (float)i0;
        const float2 tv = tab2[(size_t)i0 * NF + lane];
        const float filt = fmaf(fr, tv.y - tv.x, tv.x);
        const float hv = h[(size_t)sj * NF + lane];
        atomicAdd(agg + (size_t)dj * NF + lane, hv * filt);
    }
}

// ---------------------------------------------------------------------------
// fallback edge kernel (direct atomic scatter-add) — used only if ws too small
// ---------------------------------------------------------------------------
__global__ void edge_k(const int* __restrict__ nbr, const float* __restrict__ dist,
                       const float* __restrict__ h, const float2* __restrict__ tab2,
                       float* __restrict__ agg, int n_edges) {
    const int tid = threadIdx.x;
    const int lane = tid & 63;
    const int nwaves = (gridDim.x * blockDim.x) >> 6;
    const int gw = (blockIdx.x * blockDim.x + tid) >> 6;
    const float scale = (float)(TBL - 1) / CUTF;
    const int nbatch = n_edges >> 6;
    for (int bb = gw; bb < nbatch; bb += nwaves) {
        const int e0 = bb << 6;
        int src = nbr[e0 + lane];
        int dst = nbr[n_edges + e0 + lane];
        float d = dist[e0 + lane];
        float xx = d * scale;
        int i0 = (int)xx;
        i0 = max(0, min(i0, TBL - 2));
        float frac = xx - (float)i0;
        #pragma unroll 4
        for (int j = 0; j < 64; ++j) {
            const int sj = __shfl(src, j);
            const int dj = __shfl(dst, j);
            const int ij = __shfl(i0, j);
            const float fj = __shfl(frac, j);
            const float2 tv = tab2[(size_t)ij * NF + lane];
            const float filt = fmaf(fj, tv.y - tv.x, tv.x);
            const float hv = h[(size_t)sj * NF + lane];
            atomicAdd(agg + (size_t)dj * NF + lane, hv * filt);
        }
    }
    if (gw == 0) {
        for (int e = nbatch << 6; e < n_edges; ++e) {
            const int sj = nbr[e];
            const int dj = nbr[n_edges + e];
            const float d = dist[e];
            float xx = d * scale;
            int ij = (int)xx;
            ij = max(0, min(ij, TBL - 2));
            const float fj = xx - (float)ij;
            const float2 tv = tab2[(size_t)ij * NF + lane];
            const float filt = fmaf(fj, tv.y - tv.x, tv.x);
            const float hv = h[(size_t)sj * NF + lane];
            atomicAdd(agg + (size_t)dj * NF + lane, hv * filt);
        }
    }
}

// ---------------------------------------------------------------------------
// out = ssp(agg @ m_w1.T + m_b1) @ m_w2.T + m_b2  (wave/node, weights in VGPR)
// ---------------------------------------------------------------------------
__global__ void __launch_bounds__(256) out_mlp_k(const float* __restrict__ agg,
                                                 const float* __restrict__ w1,
                                                 const float* __restrict__ b1,
                                                 const float* __restrict__ w2,
                                                 const float* __restrict__ b2,
                                                 float* __restrict__ out, int n_nodes) {
    const int tid = threadIdx.x;
    const int lane = tid & 63;
    float w1reg[NF], w2reg[NF];
    #pragma unroll
    for (int k = 0; k < NF; k += 4) {
        float4 q1 = *(const float4*)(w1 + (size_t)lane * NF + k);
        w1reg[k] = q1.x; w1reg[k + 1] = q1.y; w1reg[k + 2] = q1.z; w1reg[k + 3] = q1.w;
        float4 q2 = *(const float4*)(w2 + (size_t)lane * NF + k);
        w2reg[k] = q2.x; w2reg[k + 1] = q2.y; w2reg[k + 2] = q2.z; w2reg[k + 3] = q2.w;
    }
    const float bias1 = b1[lane], bias2 = b2[lane];
    const int nwaves = (gridDim.x * blockDim.x) >> 6;
    const int gw = (blockIdx.x * blockDim.x + tid) >> 6;
    for (int n = gw; n < n_nodes; n += nwaves) {
        const float av = agg[(size_t)n * NF + lane];
        float a0 = bias1, a1 = 0.f, a2 = 0.f, a3 = 0.f;
        #pragma unroll
        for (int k = 0; k < NF; k += 4) {
            a0 = fmaf(bcast(av, k),     w1reg[k],     a0);
            a1 = fmaf(bcast(av, k + 1), w1reg[k + 1], a1);
            a2 = fmaf(bcast(av, k + 2), w1reg[k + 2], a2);
            a3 = fmaf(bcast(av, k + 3), w1reg[k + 3], a3);
        }
        const float s = sspf((a0 + a1) + (a2 + a3));
        float o0 = bias2, o1 = 0.f, o2 = 0.f, o3 = 0.f;
        #pragma unroll
        for (int k = 0; k < NF; k += 4) {
            o0 = fmaf(bcast(s, k),     w2reg[k],     o0);
            o1 = fmaf(bcast(s, k + 1), w2reg[k + 1], o1);
            o2 = fmaf(bcast(s, k + 2), w2reg[k + 2], o2);
            o3 = fmaf(bcast(s, k + 3), w2reg[k + 3], o3);
        }
        out[(size_t)n * NF + lane] = (o0 + o1) + (o2 + o3);
    }
}

extern "C" void kernel_launch(void* const* d_in, const int* in_sizes, int n_in,
                              void* d_out, int out_size, void* d_ws, size_t ws_size,
                              hipStream_t stream) {
    const int*   nbr   = (const int*)d_in[0];
    const float* dist  = (const float*)d_in[1];
    const float* x     = (const float*)d_in[2];
    const float* lin_w = (const float*)d_in[3];
    const float* lin_b = (const float*)d_in[4];
    const float* f_w1  = (const float*)d_in[5];
    const float* f_b1  = (const float*)d_in[6];
    const float* f_w2  = (const float*)d_in[7];
    const float* f_b2  = (const float*)d_in[8];
    const float* m_w1  = (const float*)d_in[9];
    const float* m_b1  = (const float*)d_in[10];
    const float* m_w2  = (const float*)d_in[11];
    const float* m_b2  = (const float*)d_in[12];

    const int n_edges = in_sizes[1];
    const int n_nodes = in_sizes[2] / NF;

    float* out = (float*)d_out;
    float* h   = out;  // h lives in d_out (dead once apply/oflow done)

    // workspace layout: agg | tab2 | gcur | oflow_cnt | oflow | payload(rest)
    char* ws = (char*)d_ws;
    size_t off = 0;
    auto alloc = [&](size_t bytes) { char* p = ws + off; off = (off + bytes + 255) & ~(size_t)255; return p; };
    float*    agg       = (float*)alloc((size_t)n_nodes * NF * sizeof(float));
    float2*   tab2      = (float2*)alloc((size_t)TBL * NF * sizeof(float2));
    unsigned* gcur      = (unsigned*)alloc((size_t)SLOTS * sizeof(unsigned));
    unsigned* oflow_cnt = (unsigned*)alloc(sizeof(unsigned));
    unsigned* oflow     = (unsigned*)alloc((size_t)OFLOW_MAX * sizeof(unsigned));
    uint2*    payload   = (uint2*)(ws + off);

    long long avail = (long long)ws_size - (long long)off;
    long long cap_ll = 0;
    if (avail > 0) cap_ll = avail / ((long long)SLOTS * (long long)sizeof(uint2));
    const int cap = (int)(cap_ll > 24000 ? 24000 : cap_ll);
    const bool bucket_path = (cap >= MIN_CAP) && (n_nodes <= (1 << 17)) && (n_nodes >= PPARTS);

    build_tab2_k<<<TBL, 64, 0, stream>>>(f_w1, f_b1, f_w2, f_b2, tab2);
    hipMemsetAsync(agg, 0, (size_t)n_nodes * NF * sizeof(float), stream);
    prep_k<<<2048, 256, 0, stream>>>(x, lin_w, lin_b, h, n_nodes);

    if (bucket_path) {
        const unsigned part_mul =
            (unsigned)(((unsigned long long)PPARTS << 32) / (unsigned long long)n_nodes);
        hipMemsetAsync(gcur, 0, (char*)(oflow_cnt + 1) - (char*)gcur, stream);
        scatter_k<<<2048, 256, 0, stream>>>(nbr, dist, part_mul, gcur, payload, cap,
                                            oflow_cnt, oflow, n_edges);
        apply_k<<<4096, 256, 0, stream>>>(gcur, payload, cap, h, tab2, agg);
        oflow_fix_k<<<64, 256, 0, stream>>>(oflow_cnt, oflow, nbr, dist, h, tab2, agg, n_edges);
    } else {
        edge_k<<<2048, 256, 0, stream>>>(nbr, dist, h, tab2, agg, n_edges);
    }
    out_mlp_k<<<1024, 256, 0, stream>>>(agg, m_w1, m_b1, m_w2, m_b2, out, n_nodes);
}

// Round 6
// 582.592 us; speedup vs baseline: 5.7333x; 5.7333x over previous
//
#include <hip/hip_runtime.h>

#define NF 64
#define KEXP 50
#define TBL 2048
#define CUTF 5.0f
#define LOG2C 0.6931471805599453f
#define GRP 64              // nodes per group (slot granule)
#define NSUB 8              // writer sub-buckets per group (blockIdx&7 ~ XCD)
#define PPARTS 16           // apply partitions (contiguous group ranges)
#define OFLOW_MAX (1 << 17)
#define MIN_CAP 112

__device__ __forceinline__ float sspf(float x) {
    return fmaxf(x, 0.0f) + log1pf(expf(-fabsf(x))) - LOG2C;
}

__device__ __forceinline__ float bcast(float v, int k) {
    return __int_as_float(__builtin_amdgcn_readlane(__float_as_int(v), k));
}

// ---------------------------------------------------------------------------
// interleaved lerp table: tab2[t][lane] = (filt_t[lane], filt_{t+1}[lane])
// ---------------------------------------------------------------------------
__global__ void build_tab2_k(const float* __restrict__ f_w1, const float* __restrict__ f_b1,
                             const float* __restrict__ f_w2, const float* __restrict__ f_b2,
                             float2* __restrict__ tab2) {
    __shared__ float rbf_s[KEXP];
    __shared__ float s_s[NF];
    const int t = blockIdx.x;
    const int f = threadIdx.x; // 0..63
    const float d = (float)t * (CUTF / (float)(TBL - 1));
    const float delta = CUTF / (float)(KEXP - 1);
    const float coeff = -0.5f / (delta * delta);
    if (f < KEXP) {
        float dd = d - (float)f * delta;
        rbf_s[f] = expf(coeff * dd * dd);
    }
    __syncthreads();
    float t1 = f_b1[f];
    for (int k = 0; k < KEXP; ++k) t1 = fmaf(rbf_s[k], f_w1[f * KEXP + k], t1);
    s_s[f] = sspf(t1);
    __syncthreads();
    float t2 = f_b2[f];
    for (int k = 0; k < NF; ++k) t2 = fmaf(s_s[k], f_w2[f * NF + k], t2);
    if (t < TBL - 1) tab2[(size_t)t * NF + f].x = t2;
    if (t > 0)       tab2[(size_t)(t - 1) * NF + f].y = t2;
}

// ---------------------------------------------------------------------------
// prep: h = x @ lin_w.T + lin_b  (wave/node, weights in VGPR, readlane bcast)
// ---------------------------------------------------------------------------
__global__ void __launch_bounds__(256) prep_k(
    const float* __restrict__ x, const float* __restrict__ w, const float* __restrict__ b,
    float* __restrict__ h, int n_nodes)
{
    const int tid = threadIdx.x;
    const int lane = tid & 63;
    float wreg[NF];
    #pragma unroll
    for (int k = 0; k < NF; k += 4) {
        float4 q = *(const float4*)(w + (size_t)lane * NF + k);
        wreg[k] = q.x; wreg[k + 1] = q.y; wreg[k + 2] = q.z; wreg[k + 3] = q.w;
    }
    const float bias = b[lane];
    const int nwaves = (gridDim.x * blockDim.x) >> 6;
    const int gw = (blockIdx.x * blockDim.x + tid) >> 6;
    for (int n = gw; n < n_nodes; n += nwaves) {
        const float xv = x[(size_t)n * NF + lane];
        float a0 = bias, a1 = 0.f, a2 = 0.f, a3 = 0.f;
        #pragma unroll
        for (int k = 0; k < NF; k += 4) {
            a0 = fmaf(bcast(xv, k),     wreg[k],     a0);
            a1 = fmaf(bcast(xv, k + 1), wreg[k + 1], a1);
            a2 = fmaf(bcast(xv, k + 2), wreg[k + 2], a2);
            a3 = fmaf(bcast(xv, k + 3), wreg[k + 3], a3);
        }
        h[(size_t)n * NF + lane] = (a0 + a1) + (a2 + a3);
    }
}

// ---------------------------------------------------------------------------
// scatter: 8B self-contained records into (dst-group, writer-sub) buckets.
// 12504 cursors -> ~128 increments each (contention-free, round-4 verified).
// rec = (src | i0<<20, dst | f15<<17)
// ---------------------------------------------------------------------------
__global__ void __launch_bounds__(256) scatter_k(const int* __restrict__ nbr,
                                                 const float* __restrict__ dist,
                                                 unsigned* __restrict__ gcur,
                                                 unsigned long long* __restrict__ payload,
                                                 int cap,
                                                 unsigned* __restrict__ oflow_cnt,
                                                 unsigned* __restrict__ oflow, int n_edges) {
    const unsigned sub = blockIdx.x & (NSUB - 1);
    const float scale = (float)(TBL - 1) / CUTF;
    const int gt = blockIdx.x * blockDim.x + threadIdx.x;
    const int gs = gridDim.x * blockDim.x;
    for (int e = gt; e < n_edges; e += gs) {
        const unsigned dst = (unsigned)nbr[n_edges + e];
        const unsigned src = (unsigned)nbr[e];
        const float xx = dist[e] * scale;
        int i0 = (int)xx;
        i0 = max(0, min(i0, TBL - 2));
        const float fr = xx - (float)i0;
        const unsigned f15 = min((unsigned)(fr * 32768.0f), 32767u);
        const unsigned slot = (dst >> 6) * NSUB + sub;
        const unsigned pos = atomicAdd(&gcur[slot], 1u);
        if ((int)pos < cap) {
            const unsigned long long rec =
                (unsigned long long)(src | ((unsigned)i0 << 20)) |
                ((unsigned long long)(dst | (f15 << 17)) << 32);
            __builtin_nontemporal_store(rec, payload + (size_t)slot * cap + pos);
        } else {
            const unsigned oi = atomicAdd(oflow_cnt, 1u);
            if (oi < OFLOW_MAX) oflow[oi] = (unsigned)e;
        }
    }
}

// ---------------------------------------------------------------------------
// apply: partition = contiguous group range; part = (b&7)+8*(b>>11) so each
// agg slice (~1.6MB) is written by one XCD -> atomics stay in its L2.
// h/payload via nontemporal loads (keep L2 for agg + tab2).
// ---------------------------------------------------------------------------
__global__ void __launch_bounds__(256) apply_k(const unsigned* __restrict__ gcur,
                                               const unsigned long long* __restrict__ payload,
                                               int cap,
                                               const float* __restrict__ h,
                                               const float2* __restrict__ tab2,
                                               float* __restrict__ agg, int ngroups) {
    __shared__ unsigned long long rb[4][64];
    const int tid = threadIdx.x;
    const int lane = tid & 63;
    const int wid = tid >> 6;
    const int b = blockIdx.x;
    const int part = (b & 7) + 8 * (b >> 11);          // 0..15
    const int gpp = (ngroups + PPARTS - 1) / PPARTS;
    const int g0 = part * gpp;
    const int g1 = min(g0 + gpp, ngroups);
    if (g0 >= g1) return;
    const int nslots = (g1 - g0) * NSUB;
    const int waveid = ((b >> 3) & 255) * 4 + wid;     // 0..1023
    const int slot0 = g0 * NSUB;

    for (int si = waveid; si < nslots; si += 1024) {
        const int slot = slot0 + si;
        const unsigned cnt = min(gcur[slot], (unsigned)cap);
        const unsigned long long* pp = payload + (size_t)slot * cap;
        for (unsigned base = 0; base < cnt; base += 64u) {
            const int m = (int)min(64u, cnt - base);
            unsigned long long pl = 0ull;
            if (lane < m) pl = __builtin_nontemporal_load(pp + base + lane);
            rb[wid][lane] = pl;
            auto edge = [&](int j) {
                const unsigned long long r = rb[wid][j];   // uniform addr -> broadcast
                const unsigned lo = (unsigned)r;
                const unsigned hi = (unsigned)(r >> 32);
                const unsigned src = lo & 0xFFFFFu;
                const int      i0  = (int)(lo >> 20);
                const unsigned dst = hi & 0x1FFFFu;
                const float    fr  = (float)(hi >> 17) * (1.0f / 32768.0f);
                const float2 t = tab2[(size_t)i0 * NF + lane];
                const float hv = __builtin_nontemporal_load(h + (size_t)src * NF + lane);
                const float filt = fmaf(fr, t.y - t.x, t.x);
                atomicAdd(agg + (size_t)dst * NF + lane, hv * filt);
            };
            if (m == 64) {
                #pragma unroll 4
                for (int j = 0; j < 64; ++j) edge(j);
            } else {
                for (int j = 0; j < m; ++j) edge(j);
            }
        }
    }
}

// ---------------------------------------------------------------------------
// overflow fixup: global atomic adds (normally 0 edges)
// ---------------------------------------------------------------------------
__global__ void __launch_bounds__(256) oflow_fix_k(const unsigned* __restrict__ oflow_cnt,
                                                   const unsigned* __restrict__ oflow,
                                                   const int* __restrict__ nbr,
                                                   const float* __restrict__ dist,
                                                   const float* __restrict__ h,
                                                   const float2* __restrict__ tab2,
                                                   float* __restrict__ agg, int n_edges) {
    const unsigned cnt = min(*oflow_cnt, (unsigned)OFLOW_MAX);
    const int lane = threadIdx.x & 63;
    const int gw = (blockIdx.x * blockDim.x + threadIdx.x) >> 6;
    const int nw = (gridDim.x * blockDim.x) >> 6;
    const float scale = (float)(TBL - 1) / CUTF;
    for (unsigned t = gw; t < cnt; t += nw) {
        const unsigned e = oflow[t];
        const int sj = nbr[e];
        const int dj = nbr[n_edges + e];
        const float xx = dist[e] * scale;
        int i0 = (int)xx;
        i0 = max(0, min(i0, TBL - 2));
        const float fr = xx - (float)i0;
        const float2 tv = tab2[(size_t)i0 * NF + lane];
        const float filt = fmaf(fr, tv.y - tv.x, tv.x);
        const float hv = h[(size_t)sj * NF + lane];
        atomicAdd(agg + (size_t)dj * NF + lane, hv * filt);
    }
}

// ---------------------------------------------------------------------------
// fallback edge kernel (direct atomic scatter-add) — used only if ws too small
// ---------------------------------------------------------------------------
__global__ void edge_k(const int* __restrict__ nbr, const float* __restrict__ dist,
                       const float* __restrict__ h, const float2* __restrict__ tab2,
                       float* __restrict__ agg, int n_edges) {
    const int tid = threadIdx.x;
    const int lane = tid & 63;
    const int nwaves = (gridDim.x * blockDim.x) >> 6;
    const int gw = (blockIdx.x * blockDim.x + tid) >> 6;
    const float scale = (float)(TBL - 1) / CUTF;
    const int nbatch = n_edges >> 6;
    for (int bb = gw; bb < nbatch; bb += nwaves) {
        const int e0 = bb << 6;
        int src = nbr[e0 + lane];
        int dst = nbr[n_edges + e0 + lane];
        float d = dist[e0 + lane];
        float xx = d * scale;
        int i0 = (int)xx;
        i0 = max(0, min(i0, TBL - 2));
        float frac = xx - (float)i0;
        #pragma unroll 4
        for (int j = 0; j < 64; ++j) {
            const int sj = __shfl(src, j);
            const int dj = __shfl(dst, j);
            const int ij = __shfl(i0, j);
            const float fj = __shfl(frac, j);
            const float2 tv = tab2[(size_t)ij * NF + lane];
            const float filt = fmaf(fj, tv.y - tv.x, tv.x);
            const float hv = h[(size_t)sj * NF + lane];
            atomicAdd(agg + (size_t)dj * NF + lane, hv * filt);
        }
    }
    if (gw == 0) {
        for (int e = nbatch << 6; e < n_edges; ++e) {
            const int sj = nbr[e];
            const int dj = nbr[n_edges + e];
            const float d = dist[e];
            float xx = d * scale;
            int ij = (int)xx;
            ij = max(0, min(ij, TBL - 2));
            const float fj = xx - (float)ij;
            const float2 tv = tab2[(size_t)ij * NF + lane];
            const float filt = fmaf(fj, tv.y - tv.x, tv.x);
            const float hv = h[(size_t)sj * NF + lane];
            atomicAdd(agg + (size_t)dj * NF + lane, hv * filt);
        }
    }
}

// ---------------------------------------------------------------------------
// out = ssp(agg @ m_w1.T + m_b1) @ m_w2.T + m_b2  (wave/node, weights in VGPR)
// ---------------------------------------------------------------------------
__global__ void __launch_bounds__(256) out_mlp_k(const float* __restrict__ agg,
                                                 const float* __restrict__ w1,
                                                 const float* __restrict__ b1,
                                                 const float* __restrict__ w2,
                                                 const float* __restrict__ b2,
                                                 float* __restrict__ out, int n_nodes) {
    const int tid = threadIdx.x;
    const int lane = tid & 63;
    float w1reg[NF], w2reg[NF];
    #pragma unroll
    for (int k = 0; k < NF; k += 4) {
        float4 q1 = *(const float4*)(w1 + (size_t)lane * NF + k);
        w1reg[k] = q1.x; w1reg[k + 1] = q1.y; w1reg[k + 2] = q1.z; w1reg[k + 3] = q1.w;
        float4 q2 = *(const float4*)(w2 + (size_t)lane * NF + k);
        w2reg[k] = q2.x; w2reg[k + 1] = q2.y; w2reg[k + 2] = q2.z; w2reg[k + 3] = q2.w;
    }
    const float bias1 = b1[lane], bias2 = b2[lane];
    const int nwaves = (gridDim.x * blockDim.x) >> 6;
    const int gw = (blockIdx.x * blockDim.x + tid) >> 6;
    for (int n = gw; n < n_nodes; n += nwaves) {
        const float av = agg[(size_t)n * NF + lane];
        float a0 = bias1, a1 = 0.f, a2 = 0.f, a3 = 0.f;
        #pragma unroll
        for (int k = 0; k < NF; k += 4) {
            a0 = fmaf(bcast(av, k),     w1reg[k],     a0);
            a1 = fmaf(bcast(av, k + 1), w1reg[k + 1], a1);
            a2 = fmaf(bcast(av, k + 2), w1reg[k + 2], a2);
            a3 = fmaf(bcast(av, k + 3), w1reg[k + 3], a3);
        }
        const float s = sspf((a0 + a1) + (a2 + a3));
        float o0 = bias2, o1 = 0.f, o2 = 0.f, o3 = 0.f;
        #pragma unroll
        for (int k = 0; k < NF; k += 4) {
            o0 = fmaf(bcast(s, k),     w2reg[k],     o0);
            o1 = fmaf(bcast(s, k + 1), w2reg[k + 1], o1);
            o2 = fmaf(bcast(s, k + 2), w2reg[k + 2], o2);
            o3 = fmaf(bcast(s, k + 3), w2reg[k + 3], o3);
        }
        out[(size_t)n * NF + lane] = (o0 + o1) + (o2 + o3);
    }
}

extern "C" void kernel_launch(void* const* d_in, const int* in_sizes, int n_in,
                              void* d_out, int out_size, void* d_ws, size_t ws_size,
                              hipStream_t stream) {
    const int*   nbr   = (const int*)d_in[0];
    const float* dist  = (const float*)d_in[1];
    const float* x     = (const float*)d_in[2];
    const float* lin_w = (const float*)d_in[3];
    const float* lin_b = (const float*)d_in[4];
    const float* f_w1  = (const float*)d_in[5];
    const float* f_b1  = (const float*)d_in[6];
    const float* f_w2  = (const float*)d_in[7];
    const float* f_b2  = (const float*)d_in[8];
    const float* m_w1  = (const float*)d_in[9];
    const float* m_b1  = (const float*)d_in[10];
    const float* m_w2  = (const float*)d_in[11];
    const float* m_b2  = (const float*)d_in[12];

    const int n_edges = in_sizes[1];
    const int n_nodes = in_sizes[2] / NF;
    const int ngroups = (n_nodes + GRP - 1) / GRP;
    const int slots   = ngroups * NSUB;

    float* out = (float*)d_out;
    float* h   = out;  // h lives in d_out (dead once apply/oflow done)

    // workspace layout: agg | tab2 | gcur | oflow_cnt | oflow | payload(rest)
    char* ws = (char*)d_ws;
    size_t off = 0;
    auto alloc = [&](size_t bytes) { char* p = ws + off; off = (off + bytes + 255) & ~(size_t)255; return p; };
    float*    agg       = (float*)alloc((size_t)n_nodes * NF * sizeof(float));
    float2*   tab2      = (float2*)alloc((size_t)TBL * NF * sizeof(float2));
    unsigned* gcur      = (unsigned*)alloc((size_t)slots * sizeof(unsigned));
    unsigned* oflow_cnt = (unsigned*)alloc(sizeof(unsigned));
    unsigned* oflow     = (unsigned*)alloc((size_t)OFLOW_MAX * sizeof(unsigned));
    unsigned long long* payload = (unsigned long long*)(ws + off);

    long long avail = (long long)ws_size - (long long)off;
    long long cap_ll = 0;
    if (avail > 0) cap_ll = avail / ((long long)slots * (long long)sizeof(unsigned long long));
    const int cap = (int)(cap_ll > 256 ? 256 : cap_ll);
    const bool bucket_path = (cap >= MIN_CAP) && (n_nodes <= (1 << 17)) && (n_nodes >= 1024);

    build_tab2_k<<<TBL, 64, 0, stream>>>(f_w1, f_b1, f_w2, f_b2, tab2);
    hipMemsetAsync(agg, 0, (size_t)n_nodes * NF * sizeof(float), stream);
    prep_k<<<2048, 256, 0, stream>>>(x, lin_w, lin_b, h, n_nodes);

    if (bucket_path) {
        hipMemsetAsync(gcur, 0, (char*)(oflow_cnt + 1) - (char*)gcur, stream);
        scatter_k<<<2048, 256, 0, stream>>>(nbr, dist, gcur, payload, cap,
                                            oflow_cnt, oflow, n_edges);
        apply_k<<<4096, 256, 0, stream>>>(gcur, payload, cap, h, tab2, agg, ngroups);
        oflow_fix_k<<<64, 256, 0, stream>>>(oflow_cnt, oflow, nbr, dist, h, tab2, agg, n_edges);
    } else {
        edge_k<<<2048, 256, 0, stream>>>(nbr, dist, h, tab2, agg, n_edges);
    }
    out_mlp_k<<<1024, 256, 0, stream>>>(agg, m_w1, m_b1, m_w2, m_b2, out, n_nodes);
}

// Round 7
// 316.557 us; speedup vs baseline: 10.5515x; 1.8404x over previous
//
#include <hip/hip_runtime.h>

#define NF 64
#define KEXP 50
#define TBL 2048
#define CUTF 5.0f
#define LOG2C 0.6931471805599453f
#define GRP 64              // nodes per group (slot granule)
#define NSUB 8              // writer sub-buckets per group (blockIdx&7 ~ XCD)
#define OFLOW_MAX (1 << 17)
#define MIN_CAP 160

__device__ __forceinline__ float sspf(float x) {
    return fmaxf(x, 0.0f) + log1pf(expf(-fabsf(x))) - LOG2C;
}

__device__ __forceinline__ float bcast(float v, int k) {
    return __int_as_float(__builtin_amdgcn_readlane(__float_as_int(v), k));
}

// ---------------------------------------------------------------------------
// interleaved lerp table: tab2[t][lane] = (filt_t[lane], filt_{t+1}[lane])
// ---------------------------------------------------------------------------
__global__ void build_tab2_k(const float* __restrict__ f_w1, const float* __restrict__ f_b1,
                             const float* __restrict__ f_w2, const float* __restrict__ f_b2,
                             float2* __restrict__ tab2) {
    __shared__ float rbf_s[KEXP];
    __shared__ float s_s[NF];
    const int t = blockIdx.x;
    const int f = threadIdx.x; // 0..63
    const float d = (float)t * (CUTF / (float)(TBL - 1));
    const float delta = CUTF / (float)(KEXP - 1);
    const float coeff = -0.5f / (delta * delta);
    if (f < KEXP) {
        float dd = d - (float)f * delta;
        rbf_s[f] = expf(coeff * dd * dd);
    }
    __syncthreads();
    float t1 = f_b1[f];
    for (int k = 0; k < KEXP; ++k) t1 = fmaf(rbf_s[k], f_w1[f * KEXP + k], t1);
    s_s[f] = sspf(t1);
    __syncthreads();
    float t2 = f_b2[f];
    for (int k = 0; k < NF; ++k) t2 = fmaf(s_s[k], f_w2[f * NF + k], t2);
    if (t < TBL - 1) tab2[(size_t)t * NF + f].x = t2;
    if (t > 0)       tab2[(size_t)(t - 1) * NF + f].y = t2;
}

// ---------------------------------------------------------------------------
// prep: h = x @ lin_w.T + lin_b  (wave/node, weights in VGPR, readlane bcast)
// ---------------------------------------------------------------------------
__global__ void __launch_bounds__(256) prep_k(
    const float* __restrict__ x, const float* __restrict__ w, const float* __restrict__ b,
    float* __restrict__ h, int n_nodes)
{
    const int tid = threadIdx.x;
    const int lane = tid & 63;
    float wreg[NF];
    #pragma unroll
    for (int k = 0; k < NF; k += 4) {
        float4 q = *(const float4*)(w + (size_t)lane * NF + k);
        wreg[k] = q.x; wreg[k + 1] = q.y; wreg[k + 2] = q.z; wreg[k + 3] = q.w;
    }
    const float bias = b[lane];
    const int nwaves = (gridDim.x * blockDim.x) >> 6;
    const int gw = (blockIdx.x * blockDim.x + tid) >> 6;
    for (int n = gw; n < n_nodes; n += nwaves) {
        const float xv = x[(size_t)n * NF + lane];
        float a0 = bias, a1 = 0.f, a2 = 0.f, a3 = 0.f;
        #pragma unroll
        for (int k = 0; k < NF; k += 4) {
            a0 = fmaf(bcast(xv, k),     wreg[k],     a0);
            a1 = fmaf(bcast(xv, k + 1), wreg[k + 1], a1);
            a2 = fmaf(bcast(xv, k + 2), wreg[k + 2], a2);
            a3 = fmaf(bcast(xv, k + 3), wreg[k + 3], a3);
        }
        h[(size_t)n * NF + lane] = (a0 + a1) + (a2 + a3);
    }
}

// ---------------------------------------------------------------------------
// scatter: 8B self-contained records into (dst-group, writer-sub) buckets.
// rec = (src | i0<<20, dst | f15<<17)
// ---------------------------------------------------------------------------
__global__ void __launch_bounds__(256) scatter_k(const int* __restrict__ nbr,
                                                 const float* __restrict__ dist,
                                                 unsigned* __restrict__ gcur,
                                                 unsigned long long* __restrict__ payload,
                                                 int cap,
                                                 unsigned* __restrict__ oflow_cnt,
                                                 unsigned* __restrict__ oflow, int n_edges) {
    const unsigned sub = blockIdx.x & (NSUB - 1);
    const float scale = (float)(TBL - 1) / CUTF;
    const int gt = blockIdx.x * blockDim.x + threadIdx.x;
    const int gs = gridDim.x * blockDim.x;
    for (int e = gt; e < n_edges; e += gs) {
        const unsigned dst = (unsigned)nbr[n_edges + e];
        const unsigned src = (unsigned)nbr[e];
        const float xx = dist[e] * scale;
        int i0 = (int)xx;
        i0 = max(0, min(i0, TBL - 2));
        const float fr = xx - (float)i0;
        const unsigned f15 = min((unsigned)(fr * 32768.0f), 32767u);
        const unsigned slot = (dst >> 6) * NSUB + sub;
        const unsigned pos = atomicAdd(&gcur[slot], 1u);
        if ((int)pos < cap) {
            const unsigned long long rec =
                (unsigned long long)(src | ((unsigned)i0 << 20)) |
                ((unsigned long long)(dst | (f15 << 17)) << 32);
            __builtin_nontemporal_store(rec, payload + (size_t)slot * cap + pos);
        } else {
            const unsigned oi = atomicAdd(oflow_cnt, 1u);
            if (oi < OFLOW_MAX) oflow[oi] = (unsigned)e;
        }
    }
}

// ---------------------------------------------------------------------------
// agg: block = 64-node group. Phase A: count rows. Phase B: in-LDS counting
// sort of records by row. Phase C: pure gather-accumulate per row (NO atomics
// in the hot loop), register acc, one coalesced store per row.
// ---------------------------------------------------------------------------
__global__ void __launch_bounds__(256) agg_k(const unsigned* __restrict__ gcur,
                                             const unsigned long long* __restrict__ payload,
                                             int cap,
                                             const float* __restrict__ h,
                                             const float2* __restrict__ tab2,
                                             float* __restrict__ agg, int n_nodes) {
    __shared__ unsigned long long sorted_s[GRP * 32];   // 2048 recs = 16KB (8*cap max)
    __shared__ unsigned cnt_s[GRP];
    __shared__ unsigned base_s[GRP];
    __shared__ unsigned cur_s[GRP];
    const int tid = threadIdx.x;
    const int lane = tid & 63;
    const int wid = tid >> 6;   // 0..3
    const int g = blockIdx.x;

    if (tid < GRP) cnt_s[tid] = 0u;
    __syncthreads();

    // Phase A: count records per dst-row
    for (int sb = wid; sb < NSUB; sb += 4) {
        const int slot = g * NSUB + sb;
        const unsigned cnt = min(gcur[slot], (unsigned)cap);
        const unsigned long long* pp = payload + (size_t)slot * cap;
        for (unsigned i = lane; i < cnt; i += 64u) {
            const unsigned long long rec = __builtin_nontemporal_load(pp + i);
            atomicAdd(&cnt_s[(unsigned)(rec >> 32) & 63u], 1u);
        }
    }
    __syncthreads();

    // exclusive scan over 64 row counts (one wave)
    if (tid < GRP) {
        const unsigned c = cnt_s[tid];
        unsigned run = c;
        #pragma unroll
        for (int d = 1; d < 64; d <<= 1) {
            const unsigned t = __shfl_up(run, d, 64);
            if (tid >= d) run += t;
        }
        base_s[tid] = run - c;
        cur_s[tid]  = run - c;
    }
    __syncthreads();

    // Phase B: counting-sort records into contiguous per-row runs in LDS
    for (int sb = wid; sb < NSUB; sb += 4) {
        const int slot = g * NSUB + sb;
        const unsigned cnt = min(gcur[slot], (unsigned)cap);
        const unsigned long long* pp = payload + (size_t)slot * cap;
        for (unsigned i = lane; i < cnt; i += 64u) {
            const unsigned long long rec = __builtin_nontemporal_load(pp + i);
            const unsigned pos = atomicAdd(&cur_s[(unsigned)(rec >> 32) & 63u], 1u);
            sorted_s[pos] = rec;
        }
    }
    __syncthreads();

    // Phase C: wave owns 16 contiguous rows; pure gather + register accumulate
    auto ev = [&](unsigned long long rec) -> float {
        const unsigned lo = (unsigned)rec;
        const unsigned src = lo & 0xFFFFFu;
        const int      i0  = (int)(lo >> 20);
        const float    fr  = (float)((unsigned)(rec >> 32) >> 17) * (1.0f / 32768.0f);
        const float2 t = tab2[(size_t)i0 * NF + lane];
        const float hv = h[(size_t)src * NF + lane];
        return hv * fmaf(fr, t.y - t.x, t.x);
    };
    const int n0 = g * GRP;
    for (int rr = 0; rr < 16; ++rr) {
        const int r = (wid << 4) + rr;
        unsigned i = base_s[r];
        const unsigned e = cur_s[r];   // == base + cnt after phase B
        float acc0 = 0.f, acc1 = 0.f;
        for (; i + 4u <= e; i += 4u) {
            const unsigned long long r0 = sorted_s[i];
            const unsigned long long r1 = sorted_s[i + 1];
            const unsigned long long r2 = sorted_s[i + 2];
            const unsigned long long r3 = sorted_s[i + 3];
            acc0 += ev(r0) + ev(r1);
            acc1 += ev(r2) + ev(r3);
        }
        for (; i < e; ++i) acc0 += ev(sorted_s[i]);
        const int n = n0 + r;
        if (n < n_nodes) agg[(size_t)n * NF + lane] = acc0 + acc1;
    }
}

// ---------------------------------------------------------------------------
// overflow fixup: global atomic adds (normally 0 edges)
// ---------------------------------------------------------------------------
__global__ void __launch_bounds__(256) oflow_fix_k(const unsigned* __restrict__ oflow_cnt,
                                                   const unsigned* __restrict__ oflow,
                                                   const int* __restrict__ nbr,
                                                   const float* __restrict__ dist,
                                                   const float* __restrict__ h,
                                                   const float2* __restrict__ tab2,
                                                   float* __restrict__ agg, int n_edges) {
    const unsigned cnt = min(*oflow_cnt, (unsigned)OFLOW_MAX);
    const int lane = threadIdx.x & 63;
    const int gw = (blockIdx.x * blockDim.x + threadIdx.x) >> 6;
    const int nw = (gridDim.x * blockDim.x) >> 6;
    const float scale = (float)(TBL - 1) / CUTF;
    for (unsigned t = gw; t < cnt; t += nw) {
        const unsigned e = oflow[t];
        const int sj = nbr[e];
        const int dj = nbr[n_edges + e];
        const float xx = dist[e] * scale;
        int i0 = (int)xx;
        i0 = max(0, min(i0, TBL - 2));
        const float fr = xx - (float)i0;
        const float2 tv = tab2[(size_t)i0 * NF + lane];
        const float filt = fmaf(fr, tv.y - tv.x, tv.x);
        const float hv = h[(size_t)sj * NF + lane];
        atomicAdd(agg + (size_t)dj * NF + lane, hv * filt);
    }
}

// ---------------------------------------------------------------------------
// fallback edge kernel (direct atomic scatter-add) — used only if ws too small
// ---------------------------------------------------------------------------
__global__ void edge_k(const int* __restrict__ nbr, const float* __restrict__ dist,
                       const float* __restrict__ h, const float2* __restrict__ tab2,
                       float* __restrict__ agg, int n_edges) {
    const int tid = threadIdx.x;
    const int lane = tid & 63;
    const int nwaves = (gridDim.x * blockDim.x) >> 6;
    const int gw = (blockIdx.x * blockDim.x + tid) >> 6;
    const float scale = (float)(TBL - 1) / CUTF;
    const int nbatch = n_edges >> 6;
    for (int bb = gw; bb < nbatch; bb += nwaves) {
        const int e0 = bb << 6;
        int src = nbr[e0 + lane];
        int dst = nbr[n_edges + e0 + lane];
        float d = dist[e0 + lane];
        float xx = d * scale;
        int i0 = (int)xx;
        i0 = max(0, min(i0, TBL - 2));
        float frac = xx - (float)i0;
        #pragma unroll 4
        for (int j = 0; j < 64; ++j) {
            const int sj = __shfl(src, j);
            const int dj = __shfl(dst, j);
            const int ij = __shfl(i0, j);
            const float fj = __shfl(frac, j);
            const float2 tv = tab2[(size_t)ij * NF + lane];
            const float filt = fmaf(fj, tv.y - tv.x, tv.x);
            const float hv = h[(size_t)sj * NF + lane];
            atomicAdd(agg + (size_t)dj * NF + lane, hv * filt);
        }
    }
    if (gw == 0) {
        for (int e = nbatch << 6; e < n_edges; ++e) {
            const int sj = nbr[e];
            const int dj = nbr[n_edges + e];
            const float d = dist[e];
            float xx = d * scale;
            int ij = (int)xx;
            ij = max(0, min(ij, TBL - 2));
            const float fj = xx - (float)ij;
            const float2 tv = tab2[(size_t)ij * NF + lane];
            const float filt = fmaf(fj, tv.y - tv.x, tv.x);
            const float hv = h[(size_t)sj * NF + lane];
            atomicAdd(agg + (size_t)dj * NF + lane, hv * filt);
        }
    }
}

// ---------------------------------------------------------------------------
// out = ssp(agg @ m_w1.T + m_b1) @ m_w2.T + m_b2  (wave/node, weights in VGPR)
// ---------------------------------------------------------------------------
__global__ void __launch_bounds__(256) out_mlp_k(const float* __restrict__ agg,
                                                 const float* __restrict__ w1,
                                                 const float* __restrict__ b1,
                                                 const float* __restrict__ w2,
                                                 const float* __restrict__ b2,
                                                 float* __restrict__ out, int n_nodes) {
    const int tid = threadIdx.x;
    const int lane = tid & 63;
    float w1reg[NF], w2reg[NF];
    #pragma unroll
    for (int k = 0; k < NF; k += 4) {
        float4 q1 = *(const float4*)(w1 + (size_t)lane * NF + k);
        w1reg[k] = q1.x; w1reg[k + 1] = q1.y; w1reg[k + 2] = q1.z; w1reg[k + 3] = q1.w;
        float4 q2 = *(const float4*)(w2 + (size_t)lane * NF + k);
        w2reg[k] = q2.x; w2reg[k + 1] = q2.y; w2reg[k + 2] = q2.z; w2reg[k + 3] = q2.w;
    }
    const float bias1 = b1[lane], bias2 = b2[lane];
    const int nwaves = (gridDim.x * blockDim.x) >> 6;
    const int gw = (blockIdx.x * blockDim.x + tid) >> 6;
    for (int n = gw; n < n_nodes; n += nwaves) {
        const float av = agg[(size_t)n * NF + lane];
        float a0 = bias1, a1 = 0.f, a2 = 0.f, a3 = 0.f;
        #pragma unroll
        for (int k = 0; k < NF; k += 4) {
            a0 = fmaf(bcast(av, k),     w1reg[k],     a0);
            a1 = fmaf(bcast(av, k + 1), w1reg[k + 1], a1);
            a2 = fmaf(bcast(av, k + 2), w1reg[k + 2], a2);
            a3 = fmaf(bcast(av, k + 3), w1reg[k + 3], a3);
        }
        const float s = sspf((a0 + a1) + (a2 + a3));
        float o0 = bias2, o1 = 0.f, o2 = 0.f, o3 = 0.f;
        #pragma unroll
        for (int k = 0; k < NF; k += 4) {
            o0 = fmaf(bcast(s, k),     w2reg[k],     o0);
            o1 = fmaf(bcast(s, k + 1), w2reg[k + 1], o1);
            o2 = fmaf(bcast(s, k + 2), w2reg[k + 2], o2);
            o3 = fmaf(bcast(s, k + 3), w2reg[k + 3], o3);
        }
        out[(size_t)n * NF + lane] = (o0 + o1) + (o2 + o3);
    }
}

extern "C" void kernel_launch(void* const* d_in, const int* in_sizes, int n_in,
                              void* d_out, int out_size, void* d_ws, size_t ws_size,
                              hipStream_t stream) {
    const int*   nbr   = (const int*)d_in[0];
    const float* dist  = (const float*)d_in[1];
    const float* x     = (const float*)d_in[2];
    const float* lin_w = (const float*)d_in[3];
    const float* lin_b = (const float*)d_in[4];
    const float* f_w1  = (const float*)d_in[5];
    const float* f_b1  = (const float*)d_in[6];
    const float* f_w2  = (const float*)d_in[7];
    const float* f_b2  = (const float*)d_in[8];
    const float* m_w1  = (const float*)d_in[9];
    const float* m_b1  = (const float*)d_in[10];
    const float* m_w2  = (const float*)d_in[11];
    const float* m_b2  = (const float*)d_in[12];

    const int n_edges = in_sizes[1];
    const int n_nodes = in_sizes[2] / NF;
    const int ngroups = (n_nodes + GRP - 1) / GRP;
    const int slots   = ngroups * NSUB;

    float* out = (float*)d_out;
    float* h   = out;  // h lives in d_out (dead once agg/oflow done)

    // workspace layout: agg | tab2 | gcur | oflow_cnt | oflow | payload(rest)
    char* ws = (char*)d_ws;
    size_t off = 0;
    auto alloc = [&](size_t bytes) { char* p = ws + off; off = (off + bytes + 255) & ~(size_t)255; return p; };
    float*    agg       = (float*)alloc((size_t)n_nodes * NF * sizeof(float));
    float2*   tab2      = (float2*)alloc((size_t)TBL * NF * sizeof(float2));
    unsigned* gcur      = (unsigned*)alloc((size_t)slots * sizeof(unsigned));
    unsigned* oflow_cnt = (unsigned*)alloc(sizeof(unsigned));
    unsigned* oflow     = (unsigned*)alloc((size_t)OFLOW_MAX * sizeof(unsigned));
    unsigned long long* payload = (unsigned long long*)(ws + off);

    long long avail = (long long)ws_size - (long long)off;
    long long cap_ll = 0;
    if (avail > 0) cap_ll = avail / ((long long)slots * (long long)sizeof(unsigned long long));
    const int cap = (int)(cap_ll > 256 ? 256 : cap_ll);
    const bool bucket_path = (cap >= MIN_CAP) && (n_nodes <= (1 << 17)) && (n_nodes >= 1024);

    build_tab2_k<<<TBL, 64, 0, stream>>>(f_w1, f_b1, f_w2, f_b2, tab2);
    prep_k<<<2048, 256, 0, stream>>>(x, lin_w, lin_b, h, n_nodes);

    if (bucket_path) {
        hipMemsetAsync(gcur, 0, (char*)(oflow_cnt + 1) - (char*)gcur, stream);
        scatter_k<<<2048, 256, 0, stream>>>(nbr, dist, gcur, payload, cap,
                                            oflow_cnt, oflow, n_edges);
        agg_k<<<ngroups, 256, 0, stream>>>(gcur, payload, cap, h, tab2, agg, n_nodes);
        oflow_fix_k<<<64, 256, 0, stream>>>(oflow_cnt, oflow, nbr, dist, h, tab2, agg, n_edges);
    } else {
        hipMemsetAsync(agg, 0, (size_t)n_nodes * NF * sizeof(float), stream);
        edge_k<<<2048, 256, 0, stream>>>(nbr, dist, h, tab2, agg, n_edges);
    }
    out_mlp_k<<<1024, 256, 0, stream>>>(agg, m_w1, m_b1, m_w2, m_b2, out, n_nodes);
}

// Round 8
// 251.342 us; speedup vs baseline: 13.2893x; 1.2595x over previous
//
#include <hip/hip_runtime.h>
#include <hip/hip_fp16.h>

#define NF 64
#define KEXP 50
#define TBL 2048
#define CUTF 5.0f
#define LOG2C 0.6931471805599453f
#define GRP 64              // nodes per group (agg block granule)
#define NCHK 512            // sort chunks
#define SORT_MAX 3200       // max edges per chunk (LDS bound)
#define GMAX 2048           // max node-groups (LDS histogram bound)
#define SCAP 1536           // max records per group in agg (mean 1024, +16 sigma)
#define OFLOW_MAX (1 << 16)

typedef unsigned long long ull;

__device__ __forceinline__ float sspf(float x) {
    return fmaxf(x, 0.0f) + log1pf(expf(-fabsf(x))) - LOG2C;
}

__device__ __forceinline__ float bcast(float v, int k) {
    return __int_as_float(__builtin_amdgcn_readlane(__float_as_int(v), k));
}

// ---------------------------------------------------------------------------
// fp16 interleaved lerp table: tabh[t][f] = (filt_t[f], filt_{t+1}[f]) as half2
// ---------------------------------------------------------------------------
__global__ void build_tabh_k(const float* __restrict__ f_w1, const float* __restrict__ f_b1,
                             const float* __restrict__ f_w2, const float* __restrict__ f_b2,
                             unsigned short* __restrict__ tabh) {
    __shared__ float rbf_s[KEXP];
    __shared__ float s_s[NF];
    const int t = blockIdx.x;
    const int f = threadIdx.x; // 0..63
    const float d = (float)t * (CUTF / (float)(TBL - 1));
    const float delta = CUTF / (float)(KEXP - 1);
    const float coeff = -0.5f / (delta * delta);
    if (f < KEXP) {
        float dd = d - (float)f * delta;
        rbf_s[f] = expf(coeff * dd * dd);
    }
    __syncthreads();
    float t1 = f_b1[f];
    for (int k = 0; k < KEXP; ++k) t1 = fmaf(rbf_s[k], f_w1[f * KEXP + k], t1);
    s_s[f] = sspf(t1);
    __syncthreads();
    float t2 = f_b2[f];
    for (int k = 0; k < NF; ++k) t2 = fmaf(s_s[k], f_w2[f * NF + k], t2);
    union { __half h; unsigned short u; } cv;
    cv.h = __float2half(t2);
    if (t < TBL - 1) tabh[((size_t)t * NF + f) * 2 + 0] = cv.u;       // .x of entry t
    if (t > 0)       tabh[((size_t)(t - 1) * NF + f) * 2 + 1] = cv.u; // .y of entry t-1
}

// ---------------------------------------------------------------------------
// prep: h16 = fp16(x @ lin_w.T + lin_b)  (wave/node, weights in VGPR)
// ---------------------------------------------------------------------------
__global__ void __launch_bounds__(256) prep_k(
    const float* __restrict__ x, const float* __restrict__ w, const float* __restrict__ b,
    __half* __restrict__ h16, int n_nodes)
{
    const int tid = threadIdx.x;
    const int lane = tid & 63;
    float wreg[NF];
    #pragma unroll
    for (int k = 0; k < NF; k += 4) {
        float4 q = *(const float4*)(w + (size_t)lane * NF + k);
        wreg[k] = q.x; wreg[k + 1] = q.y; wreg[k + 2] = q.z; wreg[k + 3] = q.w;
    }
    const float bias = b[lane];
    const int nwaves = (gridDim.x * blockDim.x) >> 6;
    const int gw = (blockIdx.x * blockDim.x + tid) >> 6;
    for (int n = gw; n < n_nodes; n += nwaves) {
        const float xv = x[(size_t)n * NF + lane];
        float a0 = bias, a1 = 0.f, a2 = 0.f, a3 = 0.f;
        #pragma unroll
        for (int k = 0; k < NF; k += 4) {
            a0 = fmaf(bcast(xv, k),     wreg[k],     a0);
            a1 = fmaf(bcast(xv, k + 1), wreg[k + 1], a1);
            a2 = fmaf(bcast(xv, k + 2), wreg[k + 2], a2);
            a3 = fmaf(bcast(xv, k + 3), wreg[k + 3], a3);
        }
        h16[(size_t)n * NF + lane] = __float2half((a0 + a1) + (a2 + a3));
    }
}

// ---------------------------------------------------------------------------
// sort_chunk: block owns a contiguous edge chunk; LDS counting-sort by
// dst-group; COALESCED payload write + per-(chunk,group) u16 offsets.
// rec = (src | i0<<20, dst | f15<<17)
// ---------------------------------------------------------------------------
__global__ void __launch_bounds__(256) sort_chunk_k(
    const int* __restrict__ nbr, const float* __restrict__ dist,
    int n_edges, int ngroups, int chk,
    ull* __restrict__ payload, unsigned short* __restrict__ offs16)
{
    __shared__ ull A[SORT_MAX];
    __shared__ ull B[SORT_MAX];
    __shared__ unsigned cnt_s[GMAX];
    __shared__ unsigned tot_s;
    const int tid = threadIdx.x;
    const int c = blockIdx.x;
    const int e0 = c * chk;
    const int e1 = min(e0 + chk, n_edges);
    const int m = max(e1 - e0, 0);
    for (int g = tid; g < ngroups; g += 256) cnt_s[g] = 0u;
    __syncthreads();
    const float scale = (float)(TBL - 1) / CUTF;
    for (int i = tid; i < m; i += 256) {
        const int e = e0 + i;
        const unsigned dst = (unsigned)nbr[n_edges + e];
        const unsigned src = (unsigned)nbr[e];
        const float xx = dist[e] * scale;
        int i0 = (int)xx;
        i0 = max(0, min(i0, TBL - 2));
        const float fr = xx - (float)i0;
        const unsigned f15 = min((unsigned)(fr * 32768.0f), 32767u);
        A[i] = (ull)(src | ((unsigned)i0 << 20)) | ((ull)(dst | (f15 << 17)) << 32);
        atomicAdd(&cnt_s[dst >> 6], 1u);
    }
    __syncthreads();
    // exclusive scan over ngroups counters (wave 0, lane-strided with carry)
    if (tid < 64) {
        unsigned carry = 0u;
        for (int base = 0; base < ngroups; base += 64) {
            const int g = base + tid;
            const unsigned v = (g < ngroups) ? cnt_s[g] : 0u;
            unsigned run = v;
            #pragma unroll
            for (int d = 1; d < 64; d <<= 1) {
                const unsigned t = __shfl_up(run, d, 64);
                if (tid >= d) run += t;
            }
            if (g < ngroups) cnt_s[g] = carry + run - v;
            carry += __shfl(run, 63, 64);
        }
        if (tid == 0) tot_s = carry;
    }
    __syncthreads();
    // write offsets (coalesced)
    {
        const size_t ob = (size_t)c * (ngroups + 1);
        for (int g = tid; g <= ngroups; g += 256)
            offs16[ob + g] = (unsigned short)((g < ngroups) ? cnt_s[g] : tot_s);
    }
    __syncthreads();
    // place A -> B (LDS scatter)
    for (int i = tid; i < m; i += 256) {
        const ull r = A[i];
        const unsigned g = ((unsigned)(r >> 32) & 0x1FFFFu) >> 6;
        const unsigned p = atomicAdd(&cnt_s[g], 1u);
        B[p] = r;
    }
    __syncthreads();
    // coalesced payload write
    const size_t pbase = (size_t)c * chk;
    for (int i = tid; i < m; i += 256) payload[pbase + i] = B[i];
}

// ---------------------------------------------------------------------------
// agg: block = 64-node group. Collect the group's runs from all chunks into
// LDS, counting-sort by row, then pure gather-accumulate (no atomics).
// ---------------------------------------------------------------------------
__global__ void __launch_bounds__(256) agg_k(
    const ull* __restrict__ payload, const unsigned short* __restrict__ offs16,
    int chk, int ngroups,
    const __half* __restrict__ h16, const __half2* __restrict__ tabh,
    float* __restrict__ agg, int n_nodes,
    unsigned* __restrict__ oflow_cnt, ull* __restrict__ oflow)
{
    __shared__ ull coll[SCAP];
    __shared__ ull sorted_s[SCAP];
    __shared__ unsigned lenp[NCHK];
    __shared__ unsigned startp[NCHK];
    __shared__ unsigned destp[NCHK + 1];
    __shared__ unsigned cnt_s[GRP];
    __shared__ unsigned base_s[GRP];
    __shared__ unsigned cur_s[GRP];
    const int tid = threadIdx.x;
    const int lane = tid & 63;
    const int wid = tid >> 6;   // 0..3
    const int g = blockIdx.x;

    // read this group's per-chunk run bounds
    for (int c = tid; c < NCHK; c += 256) {
        const size_t ob = (size_t)c * (ngroups + 1) + g;
        const unsigned o0 = offs16[ob];
        const unsigned o1 = offs16[ob + 1];
        startp[c] = o0;
        lenp[c] = o1 - o0;
    }
    if (tid < GRP) cnt_s[tid] = 0u;
    __syncthreads();
    // exclusive scan over NCHK lens (wave 0)
    if (tid < 64) {
        unsigned carry = 0u;
        for (int base = 0; base < NCHK; base += 64) {
            const int c = base + tid;
            const unsigned v = lenp[c];
            unsigned run = v;
            #pragma unroll
            for (int d = 1; d < 64; d <<= 1) {
                const unsigned t = __shfl_up(run, d, 64);
                if (tid >= d) run += t;
            }
            destp[c] = carry + run - v;
            carry += __shfl(run, 63, 64);
        }
        if (tid == 0) destp[NCHK] = carry;
    }
    __syncthreads();
    const unsigned total = destp[NCHK];
    const unsigned tot = min(total, (unsigned)SCAP);
    // collect runs into LDS (lane walks its chunk's short run)
    for (int c = tid; c < NCHK; c += 256) {
        const unsigned len = lenp[c];
        const size_t src = (size_t)c * chk + startp[c];
        const unsigned d0 = destp[c];
        for (unsigned k = 0; k < len; ++k) {
            const ull r = payload[src + k];
            const unsigned d = d0 + k;
            if (d < (unsigned)SCAP) coll[d] = r;
            else {
                const unsigned oi = atomicAdd(oflow_cnt, 1u);
                if (oi < OFLOW_MAX) oflow[oi] = r;
            }
        }
    }
    __syncthreads();
    // count rows
    for (unsigned i = tid; i < tot; i += 256u)
        atomicAdd(&cnt_s[(unsigned)(coll[i] >> 32) & 63u], 1u);
    __syncthreads();
    // exclusive scan over 64 row counts
    if (tid < GRP) {
        const unsigned c = cnt_s[tid];
        unsigned run = c;
        #pragma unroll
        for (int d = 1; d < 64; d <<= 1) {
            const unsigned t = __shfl_up(run, d, 64);
            if (tid >= d) run += t;
        }
        base_s[tid] = run - c;
        cur_s[tid]  = run - c;
    }
    __syncthreads();
    // place by row
    for (unsigned i = tid; i < tot; i += 256u) {
        const ull r = coll[i];
        const unsigned pos = atomicAdd(&cur_s[(unsigned)(r >> 32) & 63u], 1u);
        sorted_s[pos] = r;
    }
    __syncthreads();
    // pure gather-accumulate; one coalesced store per row
    auto ev = [&](ull rec) -> float {
        const unsigned lo = (unsigned)rec;
        const unsigned src = lo & 0xFFFFFu;
        const int      i0  = (int)(lo >> 20);
        const float    fr  = (float)((unsigned)(rec >> 32) >> 17) * (1.0f / 32768.0f);
        const float2 t = __half22float2(tabh[(size_t)i0 * NF + lane]);
        const float hv = __half2float(h16[(size_t)src * NF + lane]);
        return hv * fmaf(fr, t.y - t.x, t.x);
    };
    const int n0 = g * GRP;
    for (int rr = 0; rr < 16; ++rr) {
        const int r = (wid << 4) + rr;
        unsigned i = base_s[r];
        const unsigned e = cur_s[r];
        float acc0 = 0.f, acc1 = 0.f;
        for (; i + 4u <= e; i += 4u) {
            const ull r0 = sorted_s[i];
            const ull r1 = sorted_s[i + 1];
            const ull r2 = sorted_s[i + 2];
            const ull r3 = sorted_s[i + 3];
            acc0 += ev(r0) + ev(r1);
            acc1 += ev(r2) + ev(r3);
        }
        for (; i < e; ++i) acc0 += ev(sorted_s[i]);
        const int n = n0 + r;
        if (n < n_nodes) agg[(size_t)n * NF + lane] = acc0 + acc1;
    }
}

// ---------------------------------------------------------------------------
// overflow fixup: records spilled by agg collect (normally zero)
// ---------------------------------------------------------------------------
__global__ void __launch_bounds__(256) oflow_fix_k(const unsigned* __restrict__ oflow_cnt,
                                                   const ull* __restrict__ oflow,
                                                   const __half* __restrict__ h16,
                                                   const __half2* __restrict__ tabh,
                                                   float* __restrict__ agg) {
    const unsigned cnt = min(*oflow_cnt, (unsigned)OFLOW_MAX);
    const int lane = threadIdx.x & 63;
    const int gw = (blockIdx.x * blockDim.x + threadIdx.x) >> 6;
    const int nw = (gridDim.x * blockDim.x) >> 6;
    for (unsigned t = gw; t < cnt; t += nw) {
        const ull rec = oflow[t];
        const unsigned lo = (unsigned)rec;
        const unsigned hi = (unsigned)(rec >> 32);
        const unsigned src = lo & 0xFFFFFu;
        const int      i0  = (int)(lo >> 20);
        const unsigned dst = hi & 0x1FFFFu;
        const float    fr  = (float)(hi >> 17) * (1.0f / 32768.0f);
        const float2 tv = __half22float2(tabh[(size_t)i0 * NF + lane]);
        const float hv = __half2float(h16[(size_t)src * NF + lane]);
        const float filt = fmaf(fr, tv.y - tv.x, tv.x);
        atomicAdd(agg + (size_t)dst * NF + lane, hv * filt);
    }
}

// ---------------------------------------------------------------------------
// fallback edge kernel (direct atomic scatter-add) — used only if ws too small
// ---------------------------------------------------------------------------
__global__ void edge_k(const int* __restrict__ nbr, const float* __restrict__ dist,
                       const __half* __restrict__ h16, const __half2* __restrict__ tabh,
                       float* __restrict__ agg, int n_edges) {
    const int tid = threadIdx.x;
    const int lane = tid & 63;
    const int nwaves = (gridDim.x * blockDim.x) >> 6;
    const int gw = (blockIdx.x * blockDim.x + tid) >> 6;
    const float scale = (float)(TBL - 1) / CUTF;
    const int nbatch = n_edges >> 6;
    for (int bb = gw; bb < nbatch; bb += nwaves) {
        const int e0 = bb << 6;
        int src = nbr[e0 + lane];
        int dst = nbr[n_edges + e0 + lane];
        float d = dist[e0 + lane];
        float xx = d * scale;
        int i0 = (int)xx;
        i0 = max(0, min(i0, TBL - 2));
        float frac = xx - (float)i0;
        #pragma unroll 4
        for (int j = 0; j < 64; ++j) {
            const int sj = __shfl(src, j);
            const int dj = __shfl(dst, j);
            const int ij = __shfl(i0, j);
            const float fj = __shfl(frac, j);
            const float2 tv = __half22float2(tabh[(size_t)ij * NF + lane]);
            const float filt = fmaf(fj, tv.y - tv.x, tv.x);
            const float hv = __half2float(h16[(size_t)sj * NF + lane]);
            atomicAdd(agg + (size_t)dj * NF + lane, hv * filt);
        }
    }
    if (gw == 0) {
        for (int e = nbatch << 6; e < n_edges; ++e) {
            const int sj = nbr[e];
            const int dj = nbr[n_edges + e];
            const float d = dist[e];
            float xx = d * scale;
            int ij = (int)xx;
            ij = max(0, min(ij, TBL - 2));
            const float fj = xx - (float)ij;
            const float2 tv = __half22float2(tabh[(size_t)ij * NF + lane]);
            const float filt = fmaf(fj, tv.y - tv.x, tv.x);
            const float hv = __half2float(h16[(size_t)sj * NF + lane]);
            atomicAdd(agg + (size_t)dj * NF + lane, hv * filt);
        }
    }
}

// ---------------------------------------------------------------------------
// out = ssp(agg @ m_w1.T + m_b1) @ m_w2.T + m_b2  (wave/node, weights in VGPR)
// safe in-place (agg aliases out; row-local)
// ---------------------------------------------------------------------------
__global__ void __launch_bounds__(256) out_mlp_k(const float* __restrict__ agg,
                                                 const float* __restrict__ w1,
                                                 const float* __restrict__ b1,
                                                 const float* __restrict__ w2,
                                                 const float* __restrict__ b2,
                                                 float* __restrict__ out, int n_nodes) {
    const int tid = threadIdx.x;
    const int lane = tid & 63;
    float w1reg[NF], w2reg[NF];
    #pragma unroll
    for (int k = 0; k < NF; k += 4) {
        float4 q1 = *(const float4*)(w1 + (size_t)lane * NF + k);
        w1reg[k] = q1.x; w1reg[k + 1] = q1.y; w1reg[k + 2] = q1.z; w1reg[k + 3] = q1.w;
        float4 q2 = *(const float4*)(w2 + (size_t)lane * NF + k);
        w2reg[k] = q2.x; w2reg[k + 1] = q2.y; w2reg[k + 2] = q2.z; w2reg[k + 3] = q2.w;
    }
    const float bias1 = b1[lane], bias2 = b2[lane];
    const int nwaves = (gridDim.x * blockDim.x) >> 6;
    const int gw = (blockIdx.x * blockDim.x + tid) >> 6;
    for (int n = gw; n < n_nodes; n += nwaves) {
        const float av = agg[(size_t)n * NF + lane];
        float a0 = bias1, a1 = 0.f, a2 = 0.f, a3 = 0.f;
        #pragma unroll
        for (int k = 0; k < NF; k += 4) {
            a0 = fmaf(bcast(av, k),     w1reg[k],     a0);
            a1 = fmaf(bcast(av, k + 1), w1reg[k + 1], a1);
            a2 = fmaf(bcast(av, k + 2), w1reg[k + 2], a2);
            a3 = fmaf(bcast(av, k + 3), w1reg[k + 3], a3);
        }
        const float s = sspf((a0 + a1) + (a2 + a3));
        float o0 = bias2, o1 = 0.f, o2 = 0.f, o3 = 0.f;
        #pragma unroll
        for (int k = 0; k < NF; k += 4) {
            o0 = fmaf(bcast(s, k),     w2reg[k],     o0);
            o1 = fmaf(bcast(s, k + 1), w2reg[k + 1], o1);
            o2 = fmaf(bcast(s, k + 2), w2reg[k + 2], o2);
            o3 = fmaf(bcast(s, k + 3), w2reg[k + 3], o3);
        }
        out[(size_t)n * NF + lane] = (o0 + o1) + (o2 + o3);
    }
}

extern "C" void kernel_launch(void* const* d_in, const int* in_sizes, int n_in,
                              void* d_out, int out_size, void* d_ws, size_t ws_size,
                              hipStream_t stream) {
    const int*   nbr   = (const int*)d_in[0];
    const float* dist  = (const float*)d_in[1];
    const float* x     = (const float*)d_in[2];
    const float* lin_w = (const float*)d_in[3];
    const float* lin_b = (const float*)d_in[4];
    const float* f_w1  = (const float*)d_in[5];
    const float* f_b1  = (const float*)d_in[6];
    const float* f_w2  = (const float*)d_in[7];
    const float* f_b2  = (const float*)d_in[8];
    const float* m_w1  = (const float*)d_in[9];
    const float* m_b1  = (const float*)d_in[10];
    const float* m_w2  = (const float*)d_in[11];
    const float* m_b2  = (const float*)d_in[12];

    const int n_edges = in_sizes[1];
    const int n_nodes = in_sizes[2] / NF;
    const int ngroups = (n_nodes + GRP - 1) / GRP;
    const int chk     = (n_edges + NCHK - 1) / NCHK;

    float* out = (float*)d_out;
    float* agg = out;   // agg lives in d_out; out_mlp runs in place

    // workspace: h16 | tabh | offs16 | oflow_cnt | oflow | payload
    char* ws = (char*)d_ws;
    size_t off = 0;
    auto alloc = [&](size_t bytes) { char* p = ws + off; off = (off + bytes + 255) & ~(size_t)255; return p; };
    __half*         h16       = (__half*)alloc((size_t)n_nodes * NF * sizeof(__half));
    unsigned short* tabh      = (unsigned short*)alloc((size_t)TBL * NF * 2 * sizeof(unsigned short));
    unsigned short* offs16    = (unsigned short*)alloc((size_t)NCHK * (ngroups + 1) * sizeof(unsigned short));
    unsigned*       oflow_cnt = (unsigned*)alloc(sizeof(unsigned));
    ull*            oflow     = (ull*)alloc((size_t)OFLOW_MAX * sizeof(ull));
    ull*            payload   = (ull*)alloc((size_t)NCHK * chk * sizeof(ull));
    const bool sort_path = (off <= ws_size) && (chk <= SORT_MAX) && (ngroups <= GMAX) &&
                           (n_nodes <= (1 << 17)) && (n_nodes <= (1 << 20));

    build_tabh_k<<<TBL, 64, 0, stream>>>(f_w1, f_b1, f_w2, f_b2, tabh);
    prep_k<<<2048, 256, 0, stream>>>(x, lin_w, lin_b, h16, n_nodes);

    if (sort_path) {
        hipMemsetAsync(oflow_cnt, 0, sizeof(unsigned), stream);
        sort_chunk_k<<<NCHK, 256, 0, stream>>>(nbr, dist, n_edges, ngroups, chk,
                                               payload, offs16);
        agg_k<<<ngroups, 256, 0, stream>>>(payload, offs16, chk, ngroups,
                                           h16, (const __half2*)tabh, agg, n_nodes,
                                           oflow_cnt, oflow);
        oflow_fix_k<<<64, 256, 0, stream>>>(oflow_cnt, oflow, h16, (const __half2*)tabh, agg);
    } else {
        hipMemsetAsync(agg, 0, (size_t)n_nodes * NF * sizeof(float), stream);
        edge_k<<<2048, 256, 0, stream>>>(nbr, dist, h16, (const __half2*)tabh, agg, n_edges);
    }
    out_mlp_k<<<1024, 256, 0, stream>>>(agg, m_w1, m_b1, m_w2, m_b2, out, n_nodes);
}

// Round 9
// 250.575 us; speedup vs baseline: 13.3299x; 1.0031x over previous
//
#include <hip/hip_runtime.h>
#include <hip/hip_fp16.h>

#define NF 64
#define KEXP 50
#define TBL 2048
#define CUTF 5.0f
#define LOG2C 0.6931471805599453f
#define GRP 64              // nodes per group (agg block granule)
#define NSC 128             // superchunks (sort blocks)
#define GMAX 2048           // max node-groups (LDS histogram bound)
#define SCAP 1536           // max records per group in agg (mean 1024, +16 sigma)
#define OFLOW_MAX (1 << 16)

typedef unsigned long long ull;

__device__ __forceinline__ float sspf(float x) {
    return fmaxf(x, 0.0f) + log1pf(expf(-fabsf(x))) - LOG2C;
}

__device__ __forceinline__ float bcast(float v, int k) {
    return __int_as_float(__builtin_amdgcn_readlane(__float_as_int(v), k));
}

// ---------------------------------------------------------------------------
// fp16 interleaved lerp table: tabh[t][f] = (filt_t[f], filt_{t+1}[f]) as half2
// ---------------------------------------------------------------------------
__global__ void build_tabh_k(const float* __restrict__ f_w1, const float* __restrict__ f_b1,
                             const float* __restrict__ f_w2, const float* __restrict__ f_b2,
                             unsigned short* __restrict__ tabh) {
    __shared__ float rbf_s[KEXP];
    __shared__ float s_s[NF];
    const int t = blockIdx.x;
    const int f = threadIdx.x; // 0..63
    const float d = (float)t * (CUTF / (float)(TBL - 1));
    const float delta = CUTF / (float)(KEXP - 1);
    const float coeff = -0.5f / (delta * delta);
    if (f < KEXP) {
        float dd = d - (float)f * delta;
        rbf_s[f] = expf(coeff * dd * dd);
    }
    __syncthreads();
    float t1 = f_b1[f];
    for (int k = 0; k < KEXP; ++k) t1 = fmaf(rbf_s[k], f_w1[f * KEXP + k], t1);
    s_s[f] = sspf(t1);
    __syncthreads();
    float t2 = f_b2[f];
    for (int k = 0; k < NF; ++k) t2 = fmaf(s_s[k], f_w2[f * NF + k], t2);
    union { __half h; unsigned short u; } cv;
    cv.h = __float2half(t2);
    if (t < TBL - 1) tabh[((size_t)t * NF + f) * 2 + 0] = cv.u;       // .x of entry t
    if (t > 0)       tabh[((size_t)(t - 1) * NF + f) * 2 + 1] = cv.u; // .y of entry t-1
}

// ---------------------------------------------------------------------------
// prep: h16 = fp16(x @ lin_w.T + lin_b)  (wave/node, weights in VGPR)
// ---------------------------------------------------------------------------
__global__ void __launch_bounds__(256) prep_k(
    const float* __restrict__ x, const float* __restrict__ w, const float* __restrict__ b,
    __half* __restrict__ h16, int n_nodes)
{
    const int tid = threadIdx.x;
    const int lane = tid & 63;
    float wreg[NF];
    #pragma unroll
    for (int k = 0; k < NF; k += 4) {
        float4 q = *(const float4*)(w + (size_t)lane * NF + k);
        wreg[k] = q.x; wreg[k + 1] = q.y; wreg[k + 2] = q.z; wreg[k + 3] = q.w;
    }
    const float bias = b[lane];
    const int nwaves = (gridDim.x * blockDim.x) >> 6;
    const int gw = (blockIdx.x * blockDim.x + tid) >> 6;
    for (int n = gw; n < n_nodes; n += nwaves) {
        const float xv = x[(size_t)n * NF + lane];
        float a0 = bias, a1 = 0.f, a2 = 0.f, a3 = 0.f;
        #pragma unroll
        for (int k = 0; k < NF; k += 4) {
            a0 = fmaf(bcast(xv, k),     wreg[k],     a0);
            a1 = fmaf(bcast(xv, k + 1), wreg[k + 1], a1);
            a2 = fmaf(bcast(xv, k + 2), wreg[k + 2], a2);
            a3 = fmaf(bcast(xv, k + 3), wreg[k + 3], a3);
        }
        h16[(size_t)n * NF + lane] = __float2half((a0 + a1) + (a2 + a3));
    }
}

// ---------------------------------------------------------------------------
// hist: per superchunk, histogram of dst-groups + exclusive scan -> offs32
// offs[c][g] layout: [NSC][ngroups+1]
// ---------------------------------------------------------------------------
__global__ void __launch_bounds__(1024) hist_k(const int* __restrict__ nbr_dst,
                                               int n_edges, int ngroups, int chk,
                                               unsigned* __restrict__ offs) {
    __shared__ unsigned cnt_s[GMAX];
    __shared__ unsigned tot_s;
    const int tid = threadIdx.x;
    const int c = blockIdx.x;
    const int e0 = c * chk;
    const int e1 = min(e0 + chk, n_edges);
    const int m = max(e1 - e0, 0);
    for (int g = tid; g < ngroups; g += 1024) cnt_s[g] = 0u;
    __syncthreads();
    for (int i = tid; i < m; i += 1024)
        atomicAdd(&cnt_s[(unsigned)nbr_dst[e0 + i] >> 6], 1u);
    __syncthreads();
    if (tid < 64) {
        unsigned carry = 0u;
        for (int base = 0; base < ngroups; base += 64) {
            const int g = base + tid;
            const unsigned v = (g < ngroups) ? cnt_s[g] : 0u;
            unsigned run = v;
            #pragma unroll
            for (int d = 1; d < 64; d <<= 1) {
                const unsigned t = __shfl_up(run, d, 64);
                if (tid >= d) run += t;
            }
            if (g < ngroups) cnt_s[g] = carry + run - v;
            carry += __shfl(run, 63, 64);
        }
        if (tid == 0) tot_s = carry;
    }
    __syncthreads();
    const size_t ob = (size_t)c * (ngroups + 1);
    for (int g = tid; g <= ngroups; g += 1024)
        offs[ob + g] = (g < ngroups) ? cnt_s[g] : tot_s;
}

// ---------------------------------------------------------------------------
// scatter2: re-read edges, build records, write to sorted position within the
// block's OWN contiguous 100KB window (L2-resident -> lines merge).
// rec = (src | i0<<20, dst | f15<<17)
// ---------------------------------------------------------------------------
__global__ void __launch_bounds__(1024) scatter2_k(const int* __restrict__ nbr,
                                                   const float* __restrict__ dist,
                                                   int n_edges, int ngroups, int chk,
                                                   const unsigned* __restrict__ offs,
                                                   ull* __restrict__ payload) {
    __shared__ unsigned cur_s[GMAX];
    const int tid = threadIdx.x;
    const int c = blockIdx.x;
    const int e0 = c * chk;
    const int e1 = min(e0 + chk, n_edges);
    const int m = max(e1 - e0, 0);
    const size_t ob = (size_t)c * (ngroups + 1);
    for (int g = tid; g < ngroups; g += 1024) cur_s[g] = offs[ob + g];
    __syncthreads();
    const float scale = (float)(TBL - 1) / CUTF;
    const size_t pbase = (size_t)c * chk;
    for (int i = tid; i < m; i += 1024) {
        const int e = e0 + i;
        const unsigned dst = (unsigned)nbr[n_edges + e];
        const unsigned src = (unsigned)nbr[e];
        const float xx = dist[e] * scale;
        int i0 = (int)xx;
        i0 = max(0, min(i0, TBL - 2));
        const float fr = xx - (float)i0;
        const unsigned f15 = min((unsigned)(fr * 32768.0f), 32767u);
        const ull rec = (ull)(src | ((unsigned)i0 << 20)) |
                        ((ull)(dst | (f15 << 17)) << 32);
        const unsigned pos = atomicAdd(&cur_s[dst >> 6], 1u);
        payload[pbase + pos] = rec;
    }
}

// ---------------------------------------------------------------------------
// agg: block = 64-node group. Collect the group's 128 runs (~8 recs, 64-128B
// contiguous each), counting-sort by row in LDS, pure gather-accumulate.
// ---------------------------------------------------------------------------
__global__ void __launch_bounds__(256) agg_k(
    const ull* __restrict__ payload, const unsigned* __restrict__ offs,
    int chk, int ngroups,
    const __half* __restrict__ h16, const __half2* __restrict__ tabh,
    float* __restrict__ agg, int n_nodes,
    unsigned* __restrict__ oflow_cnt, ull* __restrict__ oflow)
{
    __shared__ ull coll[SCAP];
    __shared__ ull sorted_s[SCAP];
    __shared__ unsigned startp[NSC];
    __shared__ unsigned destp[NSC + 1];
    __shared__ unsigned cnt_s[GRP];
    __shared__ unsigned base_s[GRP];
    __shared__ unsigned cur_s[GRP];
    const int tid = threadIdx.x;
    const int lane = tid & 63;
    const int wid = tid >> 6;   // 0..3
    const int g = blockIdx.x;

    // run bounds per superchunk (len temporarily in destp)
    for (int c = tid; c < NSC; c += 256) {
        const size_t ob = (size_t)c * (ngroups + 1) + g;
        const unsigned o0 = offs[ob];
        const unsigned o1 = offs[ob + 1];
        startp[c] = o0;
        destp[c] = o1 - o0;
    }
    if (tid < GRP) cnt_s[tid] = 0u;
    __syncthreads();
    // exclusive scan over NSC lens (wave 0)
    if (tid < 64) {
        unsigned carry = 0u;
        for (int base = 0; base < NSC; base += 64) {
            const unsigned v = destp[base + tid];
            unsigned run = v;
            #pragma unroll
            for (int d = 1; d < 64; d <<= 1) {
                const unsigned t = __shfl_up(run, d, 64);
                if (tid >= d) run += t;
            }
            destp[base + tid] = carry + run - v;
            carry += __shfl(run, 63, 64);
        }
        if (tid == 0) destp[NSC] = carry;
    }
    __syncthreads();
    const unsigned total = destp[NSC];
    const unsigned tot = min(total, (unsigned)SCAP);
    // collect: 2 threads per superchunk, each streams a contiguous half-run
    for (int t = tid; t < NSC * 2; t += 256) {
        const int c = t >> 1, q = t & 1;
        const unsigned d0 = destp[c];
        const unsigned len = destp[c + 1] - d0;
        const unsigned half = (len + 1u) >> 1;
        const unsigned k0 = q * half;
        const unsigned k1 = min(len, k0 + half);
        const size_t srcb = (size_t)c * chk + startp[c];
        for (unsigned k = k0; k < k1; ++k) {
            const ull r = payload[srcb + k];
            const unsigned d = d0 + k;
            if (d < (unsigned)SCAP) coll[d] = r;
            else {
                const unsigned oi = atomicAdd(oflow_cnt, 1u);
                if (oi < OFLOW_MAX) oflow[oi] = r;
            }
        }
    }
    __syncthreads();
    // count rows
    for (unsigned i = tid; i < tot; i += 256u)
        atomicAdd(&cnt_s[(unsigned)(coll[i] >> 32) & 63u], 1u);
    __syncthreads();
    // exclusive scan over 64 row counts
    if (tid < GRP) {
        const unsigned c = cnt_s[tid];
        unsigned run = c;
        #pragma unroll
        for (int d = 1; d < 64; d <<= 1) {
            const unsigned t = __shfl_up(run, d, 64);
            if (tid >= d) run += t;
        }
        base_s[tid] = run - c;
        cur_s[tid]  = run - c;
    }
    __syncthreads();
    // place by row
    for (unsigned i = tid; i < tot; i += 256u) {
        const ull r = coll[i];
        const unsigned pos = atomicAdd(&cur_s[(unsigned)(r >> 32) & 63u], 1u);
        sorted_s[pos] = r;
    }
    __syncthreads();
    // pure gather-accumulate; one coalesced store per row
    auto ev = [&](ull rec) -> float {
        const unsigned lo = (unsigned)rec;
        const unsigned src = lo & 0xFFFFFu;
        const int      i0  = (int)(lo >> 20);
        const float    fr  = (float)((unsigned)(rec >> 32) >> 17) * (1.0f / 32768.0f);
        const float2 t = __half22float2(tabh[(size_t)i0 * NF + lane]);
        const float hv = __half2float(h16[(size_t)src * NF + lane]);
        return hv * fmaf(fr, t.y - t.x, t.x);
    };
    const int n0 = g * GRP;
    for (int rr = 0; rr < 16; ++rr) {
        const int r = (wid << 4) + rr;
        unsigned i = base_s[r];
        const unsigned e = cur_s[r];
        float acc0 = 0.f, acc1 = 0.f;
        for (; i + 4u <= e; i += 4u) {
            const ull r0 = sorted_s[i];
            const ull r1 = sorted_s[i + 1];
            const ull r2 = sorted_s[i + 2];
            const ull r3 = sorted_s[i + 3];
            acc0 += ev(r0) + ev(r1);
            acc1 += ev(r2) + ev(r3);
        }
        for (; i < e; ++i) acc0 += ev(sorted_s[i]);
        const int n = n0 + r;
        if (n < n_nodes) agg[(size_t)n * NF + lane] = acc0 + acc1;
    }
}

// ---------------------------------------------------------------------------
// overflow fixup: records spilled by agg collect (normally zero)
// ---------------------------------------------------------------------------
__global__ void __launch_bounds__(256) oflow_fix_k(const unsigned* __restrict__ oflow_cnt,
                                                   const ull* __restrict__ oflow,
                                                   const __half* __restrict__ h16,
                                                   const __half2* __restrict__ tabh,
                                                   float* __restrict__ agg) {
    const unsigned cnt = min(*oflow_cnt, (unsigned)OFLOW_MAX);
    const int lane = threadIdx.x & 63;
    const int gw = (blockIdx.x * blockDim.x + threadIdx.x) >> 6;
    const int nw = (gridDim.x * blockDim.x) >> 6;
    for (unsigned t = gw; t < cnt; t += nw) {
        const ull rec = oflow[t];
        const unsigned lo = (unsigned)rec;
        const unsigned hi = (unsigned)(rec >> 32);
        const unsigned src = lo & 0xFFFFFu;
        const int      i0  = (int)(lo >> 20);
        const unsigned dst = hi & 0x1FFFFu;
        const float    fr  = (float)(hi >> 17) * (1.0f / 32768.0f);
        const float2 tv = __half22float2(tabh[(size_t)i0 * NF + lane]);
        const float hv = __half2float(h16[(size_t)src * NF + lane]);
        const float filt = fmaf(fr, tv.y - tv.x, tv.x);
        atomicAdd(agg + (size_t)dst * NF + lane, hv * filt);
    }
}

// ---------------------------------------------------------------------------
// fallback edge kernel (direct atomic scatter-add) — used only if ws too small
// ---------------------------------------------------------------------------
__global__ void edge_k(const int* __restrict__ nbr, const float* __restrict__ dist,
                       const __half* __restrict__ h16, const __half2* __restrict__ tabh,
                       float* __restrict__ agg, int n_edges) {
    const int tid = threadIdx.x;
    const int lane = tid & 63;
    const int nwaves = (gridDim.x * blockDim.x) >> 6;
    const int gw = (blockIdx.x * blockDim.x + tid) >> 6;
    const float scale = (float)(TBL - 1) / CUTF;
    const int nbatch = n_edges >> 6;
    for (int bb = gw; bb < nbatch; bb += nwaves) {
        const int e0 = bb << 6;
        int src = nbr[e0 + lane];
        int dst = nbr[n_edges + e0 + lane];
        float d = dist[e0 + lane];
        float xx = d * scale;
        int i0 = (int)xx;
        i0 = max(0, min(i0, TBL - 2));
        float frac = xx - (float)i0;
        #pragma unroll 4
        for (int j = 0; j < 64; ++j) {
            const int sj = __shfl(src, j);
            const int dj = __shfl(dst, j);
            const int ij = __shfl(i0, j);
            const float fj = __shfl(frac, j);
            const float2 tv = __half22float2(tabh[(size_t)ij * NF + lane]);
            const float filt = fmaf(fj, tv.y - tv.x, tv.x);
            const float hv = __half2float(h16[(size_t)sj * NF + lane]);
            atomicAdd(agg + (size_t)dj * NF + lane, hv * filt);
        }
    }
    if (gw == 0) {
        for (int e = nbatch << 6; e < n_edges; ++e) {
            const int sj = nbr[e];
            const int dj = nbr[n_edges + e];
            const float d = dist[e];
            float xx = d * scale;
            int ij = (int)xx;
            ij = max(0, min(ij, TBL - 2));
            const float fj = xx - (float)ij;
            const float2 tv = __half22float2(tabh[(size_t)ij * NF + lane]);
            const float filt = fmaf(fj, tv.y - tv.x, tv.x);
            const float hv = __half2float(h16[(size_t)sj * NF + lane]);
            atomicAdd(agg + (size_t)dj * NF + lane, hv * filt);
        }
    }
}

// ---------------------------------------------------------------------------
// out = ssp(agg @ m_w1.T + m_b1) @ m_w2.T + m_b2  (wave/node, weights in VGPR)
// safe in-place (agg aliases out; row-local)
// ---------------------------------------------------------------------------
__global__ void __launch_bounds__(256) out_mlp_k(const float* __restrict__ agg,
                                                 const float* __restrict__ w1,
                                                 const float* __restrict__ b1,
                                                 const float* __restrict__ w2,
                                                 const float* __restrict__ b2,
                                                 float* __restrict__ out, int n_nodes) {
    const int tid = threadIdx.x;
    const int lane = tid & 63;
    float w1reg[NF], w2reg[NF];
    #pragma unroll
    for (int k = 0; k < NF; k += 4) {
        float4 q1 = *(const float4*)(w1 + (size_t)lane * NF + k);
        w1reg[k] = q1.x; w1reg[k + 1] = q1.y; w1reg[k + 2] = q1.z; w1reg[k + 3] = q1.w;
        float4 q2 = *(const float4*)(w2 + (size_t)lane * NF + k);
        w2reg[k] = q2.x; w2reg[k + 1] = q2.y; w2reg[k + 2] = q2.z; w2reg[k + 3] = q2.w;
    }
    const float bias1 = b1[lane], bias2 = b2[lane];
    const int nwaves = (gridDim.x * blockDim.x) >> 6;
    const int gw = (blockIdx.x * blockDim.x + tid) >> 6;
    for (int n = gw; n < n_nodes; n += nwaves) {
        const float av = agg[(size_t)n * NF + lane];
        float a0 = bias1, a1 = 0.f, a2 = 0.f, a3 = 0.f;
        #pragma unroll
        for (int k = 0; k < NF; k += 4) {
            a0 = fmaf(bcast(av, k),     w1reg[k],     a0);
            a1 = fmaf(bcast(av, k + 1), w1reg[k + 1], a1);
            a2 = fmaf(bcast(av, k + 2), w1reg[k + 2], a2);
            a3 = fmaf(bcast(av, k + 3), w1reg[k + 3], a3);
        }
        const float s = sspf((a0 + a1) + (a2 + a3));
        float o0 = bias2, o1 = 0.f, o2 = 0.f, o3 = 0.f;
        #pragma unroll
        for (int k = 0; k < NF; k += 4) {
            o0 = fmaf(bcast(s, k),     w2reg[k],     o0);
            o1 = fmaf(bcast(s, k + 1), w2reg[k + 1], o1);
            o2 = fmaf(bcast(s, k + 2), w2reg[k + 2], o2);
            o3 = fmaf(bcast(s, k + 3), w2reg[k + 3], o3);
        }
        out[(size_t)n * NF + lane] = (o0 + o1) + (o2 + o3);
    }
}

extern "C" void kernel_launch(void* const* d_in, const int* in_sizes, int n_in,
                              void* d_out, int out_size, void* d_ws, size_t ws_size,
                              hipStream_t stream) {
    const int*   nbr   = (const int*)d_in[0];
    const float* dist  = (const float*)d_in[1];
    const float* x     = (const float*)d_in[2];
    const float* lin_w = (const float*)d_in[3];
    const float* lin_b = (const float*)d_in[4];
    const float* f_w1  = (const float*)d_in[5];
    const float* f_b1  = (const float*)d_in[6];
    const float* f_w2  = (const float*)d_in[7];
    const float* f_b2  = (const float*)d_in[8];
    const float* m_w1  = (const float*)d_in[9];
    const float* m_b1  = (const float*)d_in[10];
    const float* m_w2  = (const float*)d_in[11];
    const float* m_b2  = (const float*)d_in[12];

    const int n_edges = in_sizes[1];
    const int n_nodes = in_sizes[2] / NF;
    const int ngroups = (n_nodes + GRP - 1) / GRP;
    const int chk     = (n_edges + NSC - 1) / NSC;

    float* out = (float*)d_out;
    float* agg = out;   // agg lives in d_out; out_mlp runs in place

    // workspace: h16 | tabh | offs32 | oflow_cnt | oflow | payload
    char* ws = (char*)d_ws;
    size_t off = 0;
    auto alloc = [&](size_t bytes) { char* p = ws + off; off = (off + bytes + 255) & ~(size_t)255; return p; };
    __half*   h16       = (__half*)alloc((size_t)n_nodes * NF * sizeof(__half));
    unsigned short* tabh = (unsigned short*)alloc((size_t)TBL * NF * 2 * sizeof(unsigned short));
    unsigned* offs      = (unsigned*)alloc((size_t)NSC * (ngroups + 1) * sizeof(unsigned));
    unsigned* oflow_cnt = (unsigned*)alloc(sizeof(unsigned));
    ull*      oflow     = (ull*)alloc((size_t)OFLOW_MAX * sizeof(ull));
    ull*      payload   = (ull*)alloc((size_t)NSC * chk * sizeof(ull));
    const bool sort_path = (off <= ws_size) && (ngroups <= GMAX) && (n_nodes <= (1 << 17));

    build_tabh_k<<<TBL, 64, 0, stream>>>(f_w1, f_b1, f_w2, f_b2, tabh);
    prep_k<<<2048, 256, 0, stream>>>(x, lin_w, lin_b, h16, n_nodes);

    if (sort_path) {
        hipMemsetAsync(oflow_cnt, 0, sizeof(unsigned), stream);
        hist_k<<<NSC, 1024, 0, stream>>>(nbr + n_edges, n_edges, ngroups, chk, offs);
        scatter2_k<<<NSC, 1024, 0, stream>>>(nbr, dist, n_edges, ngroups, chk, offs, payload);
        agg_k<<<ngroups, 256, 0, stream>>>(payload, offs, chk, ngroups,
                                           h16, (const __half2*)tabh, agg, n_nodes,
                                           oflow_cnt, oflow);
        oflow_fix_k<<<64, 256, 0, stream>>>(oflow_cnt, oflow, h16, (const __half2*)tabh, agg);
    } else {
        hipMemsetAsync(agg, 0, (size_t)n_nodes * NF * sizeof(float), stream);
        edge_k<<<2048, 256, 0, stream>>>(nbr, dist, h16, (const __half2*)tabh, agg, n_edges);
    }
    out_mlp_k<<<1024, 256, 0, stream>>>(agg, m_w1, m_b1, m_w2, m_b2, out, n_nodes);
}